// Round 12
// baseline (265.867 us; speedup 1.0000x reference)
//
#include <hip/hip_runtime.h>
#include <cstdint>
#include <cstddef>

#define C1 128
#define C2 256
#define Hh 56
#define Wd 56
#define HW 3136                  // 56*56
#define NHW 100352               // 32*3136
#define N1 ((size_t)12845056)    // 32*128*3136
#define N2 ((size_t)25690112)    // 32*256*3136
#define XPSZ ((size_t)13778944)  // 32*58*58*128
#define NREP 8                   // stat-accumulator replicas (cache-line spread)
#define NB1 392                  // conv1 grid (256-pixel tiles)
#define NB2C 392                 // conv2 grid (256-pixel tiles) -- proven-residency shape

typedef int v4i __attribute__((ext_vector_type(4)));
typedef int v16i __attribute__((ext_vector_type(16)));

// ---- workspace layout (bytes) ----
static constexpr size_t OFF_XP = 0;
static constexpr size_t OFF_Q1 = XPSZ;
static constexpr size_t OFF_Q3 = OFF_Q1 + N1;
static constexpr size_t OFF_WQ1 = OFF_Q3 + N2;
static constexpr size_t OFF_WQ2 = OFF_WQ1 + 147456;
static constexpr size_t OFF_STATS = OFF_WQ2 + 32768;

// tick counters each on their own 128B line (spin-polled); absmax separate.
struct Stats {
  int absmax1, absmax2, pad0, pad1;
  float scale1, e1, s2, e2;
  float scaleq2, e3, sf, ef;
  int padA[20];
  int tick1, padB[31];     // conv1 spin barrier
  int tick2, padC[31];     // conv2 bn2 ticket tail
  int tick3, padD[31];     // conv1 bn1 ticket tail
  int tick4, padE[31];     // conv2 spin barrier
  int sum1[NREP][C1]; unsigned sumsq1[NREP][C1];
  int min1[NREP][C1], max1[NREP][C1];
  float A1[C1], B1c[C1];
  int sum2[NREP][C2]; unsigned sumsq2[NREP][C2];
  int min2[NREP][C2], max2[NREP][C2];
  float A2[C2], B2c[C2];
};

// ---- one merged prep dispatch ----
__global__ __launch_bounds__(256) void k_pre(
    const int* __restrict__ x, signed char* __restrict__ xp,
    const float* __restrict__ wDW, signed char* __restrict__ wq1t,
    const float* __restrict__ wPW, signed char* __restrict__ wq2t,
    Stats* st) {
  __shared__ signed char lds[56 * 132];
  int t = threadIdx.x, bid = blockIdx.x;
  if (bid < 1856) {
    int hh = bid % 58, n = bid / 58;
    int* xpw = (int*)(xp + ((size_t)n * 58 + hh) * 7424);
    if (hh == 0 || hh == 57) {
      for (int o = t; o < 1856; o += 256) xpw[o] = 0;
      return;
    }
    int h = hh - 1;
    const int* xb = x + (size_t)n * C1 * HW + h * 56;
    for (int idx = t; idx < 7168; idx += 256) {
      int c = idx / 56, w = idx - c * 56;
      lds[w * 132 + c] = (signed char)xb[(size_t)c * HW + w];
    }
    __syncthreads();
    for (int o = t; o < 1856; o += 256) {
      int kb = o / 232, r = o - kb * 232, ww = r >> 2, cw = r & 3;
      int val = (ww == 0 || ww == 57) ? 0
                : *(const int*)&lds[(ww - 1) * 132 + kb * 16 + cw * 4];
      xpw[o] = val;
    }
    return;
  }
  if (bid < 2432) {
    int idx = (bid - 1856) * 256 + t;
    int co = idx / 1152, r = idx - co * 1152;
    int ci = r / 9, pos = r - ci * 9;
    int k = pos * 128 + ci;
    wq1t[(size_t)(k >> 4) * 2048 + co * 16 + (k & 15)] = (signed char)(int)wDW[idx];
    return;
  }
  if (bid < 2560) {
    int i = (bid - 2432) * 256 + t;
    int co = i >> 7, ci = i & 127;
    wq2t[(size_t)(ci >> 4) * 4096 + co * 16 + (ci & 15)] = (signed char)(int)wPW[i];
    return;
  }
  if (t == 0) {
    st->absmax1 = 0; st->absmax2 = 0;
    st->tick1 = 0; st->tick2 = 0; st->tick3 = 0; st->tick4 = 0;
  }
  for (int c = t; c < NREP * C1; c += 256) {
    ((int*)st->sum1)[c] = 0; ((unsigned*)st->sumsq1)[c] = 0u;
    ((int*)st->min1)[c] = 127; ((int*)st->max1)[c] = -128;
  }
  for (int c = t; c < NREP * C2; c += 256) {
    ((int*)st->sum2)[c] = 0; ((unsigned*)st->sumsq2)[c] = 0u;
    ((int*)st->min2)[c] = 127; ((int*)st->max2)[c] = -128;
  }
}

__device__ inline v4i ld16_lds(const signed char* p) {
  const int2* q = (const int2*)p;          // 8-byte aligned
  int2 lo = q[0], hi = q[1];
  v4i r; r[0] = lo.x; r[1] = lo.y; r[2] = hi.x; r[3] = hi.y;
  return r;
}

// bn affine from scalar stats (single call site per layer -> deterministic).
__device__ inline float bn_affine_v(int sum, unsigned sumsq, int mn, int mx,
                                    float g, float b, float e_in,
                                    float* Aout, float* Bout) {
  double meanq = (double)sum / (double)NHW;
  double varq = (double)sumsq / (double)NHW - meanq * meanq;
  float se = exp2f(e_in);
  float mean = (float)meanq * se;
  float var = (float)varq * se * se;
  float rsq = 1.0f / sqrtf(var + 1e-5f);
  float Avv = g * se * rsq;
  float Bvv = b - g * mean * rsq;
  *Aout = Avv; *Bout = Bvv;
  return fmaxf(fabsf(Avv * (float)mn + Bvv), fabsf(Avv * (float)mx + Bvv));
}

// shared conv1 MFMA body: 3x3 conv 128->128, block = 256 pixels x 128 co.
__device__ inline void conv1_mfma(const signed char* __restrict__ xp,
                                  const signed char* __restrict__ wq1t,
                                  int bx, int t, v16i a1[2][4]) {
  int lane = t & 63, wave = t >> 6;
  int half = lane >> 5, l31 = lane & 31;
  size_t g0 = (size_t)bx * 256;

  const signed char* ab[2];
#pragma unroll
  for (int i = 0; i < 2; ++i) {
    size_t gm = g0 + wave * 64 + i * 32 + l31;
    int n = (int)(gm / HW);
    int p = (int)(gm - (size_t)n * HW);
    int h = p / 56, w = p - h * 56;
    ab[i] = xp + ((size_t)n * 58 + h) * 7424 + w * 16 + half * 928;
  }
  const signed char* bb[4];
#pragma unroll
  for (int j = 0; j < 4; ++j)
    bb[j] = wq1t + (size_t)(j * 32 + l31) * 16 + half * 2048;

#pragma unroll
  for (int i = 0; i < 2; ++i)
#pragma unroll
    for (int j = 0; j < 4; ++j)
#pragma unroll
      for (int r = 0; r < 16; ++r) a1[i][j][r] = 0;

#pragma unroll
  for (int pos = 0; pos < 9; ++pos) {
    int kh = pos / 3, kw = pos - kh * 3;
    const signed char* a0p = ab[0] + kh * 7424 + kw * 16;
    const signed char* a1p = ab[1] + kh * 7424 + kw * 16;
#pragma unroll
    for (int kb = 0; kb < 8; kb += 2) {
      v4i af0 = *(const v4i*)(a0p + kb * 928);
      v4i af1 = *(const v4i*)(a1p + kb * 928);
      v4i bf[4];
#pragma unroll
      for (int j = 0; j < 4; ++j)
        bf[j] = *(const v4i*)(bb[j] + pos * 16384 + kb * 2048);
#pragma unroll
      for (int j = 0; j < 4; ++j) {
        a1[0][j] = __builtin_amdgcn_mfma_i32_32x32x32_i8(af0, bf[j], a1[0][j], 0, 0, 0);
        a1[1][j] = __builtin_amdgcn_mfma_i32_32x32x32_i8(af1, bf[j], a1[1][j], 0, 0, 0);
      }
    }
  }
}

// fused conv1: MFMA -> absmax1 -> in-kernel spin barrier -> quantize from
// registers -> q1 + replica stats -> bn1 ticket tail. (round-10 verified)
// DEADLOCK SAFETY: 392 blocks at (256,2) -> capacity 512 >= 392.
__global__ __launch_bounds__(256, 2) void k_conv1f(
    const signed char* __restrict__ xp, const signed char* __restrict__ wq1t,
    signed char* __restrict__ q1, Stats* st,
    const float* __restrict__ x_exp, const float* __restrict__ wDW_exp,
    const float* __restrict__ gamma1, const float* __restrict__ beta1) {
  __shared__ int reda[4];
  __shared__ int vbro;
  __shared__ int qti[256 * 34];            // 256 pixels x 136B
  __shared__ int psum[C1], psq[C1], pmn[C1], pmx[C1];
  __shared__ float redc[2];
  __shared__ int lastf;
  signed char* qt = (signed char*)qti;
  int t = threadIdx.x, lane = t & 63, wave = t >> 6;
  int half = lane >> 5, l31 = lane & 31;
  int rep = blockIdx.x & (NREP - 1);

  v16i a1[2][4];
  conv1_mfma(xp, wq1t, blockIdx.x, t, a1);

  int am = 0;
#pragma unroll
  for (int i = 0; i < 2; ++i)
#pragma unroll
    for (int j = 0; j < 4; ++j)
#pragma unroll
      for (int r = 0; r < 16; ++r) am = max(am, abs(a1[i][j][r]));
  for (int off = 32; off; off >>= 1) am = max(am, __shfl_down(am, off, 64));
  if (lane == 0) reda[wave] = am;
  if (t < C1) { psum[t] = 0; psq[t] = 0; pmn[t] = 127; pmx[t] = -128; }
  __syncthreads();
  if (t == 0)
    atomicMax(&st->absmax1, max(max(reda[0], reda[1]), max(reda[2], reda[3])));
  __syncthreads();                 // drains vmcnt -> absmax globally performed

  if (t == 0) {
    atomicAdd(&st->tick1, 1);
    while (atomicAdd(&st->tick1, 0) < NB1)
      __builtin_amdgcn_s_sleep(8);
    vbro = atomicAdd(&st->absmax1, 0);
  }
  __syncthreads();

  int v1 = vbro;
  int pw = 31 - __clz(v1 | 1);
  int bw = ((v1 & (v1 - 1)) == 0) ? pw : pw + 1;
  int sh = max(bw - 7, 0);
  float scale1 = exp2f((float)(-sh));
  float e1 = x_exp[0] + wDW_exp[0] + (float)sh;
  if (blockIdx.x == 0 && t == 0) st->e1 = e1;

#pragma unroll
  for (int j = 0; j < 4; ++j) {
    int sj = 0, sqj = 0, mnj = 127, mxj = -128;
    int c = j * 32 + l31;
#pragma unroll
    for (int i = 0; i < 2; ++i)
#pragma unroll
      for (int reg = 0; reg < 16; ++reg) {
        int av = a1[i][j][reg];
        int row = (reg & 3) + 8 * (reg >> 2) + 4 * half;
        int pix = wave * 64 + i * 32 + row;
        float r = rintf((float)av * scale1);
        r = fminf(fmaxf(r, -128.f), 127.f);
        int qi = (int)r;
        qt[pix * 136 + c] = (signed char)qi;
        sj += qi; sqj += qi * qi; mnj = min(mnj, qi); mxj = max(mxj, qi);
      }
    sj += __shfl_down(sj, 32, 64);
    sqj += __shfl_down(sqj, 32, 64);
    mnj = min(mnj, __shfl_down(mnj, 32, 64));
    mxj = max(mxj, __shfl_down(mxj, 32, 64));
    if (half == 0) {
      atomicAdd(&psum[c], sj); atomicAdd(&psq[c], sqj);
      atomicMin(&pmn[c], mnj); atomicMax(&pmx[c], mxj);
    }
  }
  __syncthreads();
  if (t < C1) {
    atomicAdd(&st->sum1[rep][t], psum[t]);
    atomicAdd(&st->sumsq1[rep][t], (unsigned)psq[t]);
    atomicMin(&st->min1[rep][t], pmn[t]);
    atomicMax(&st->max1[rep][t], pmx[t]);
  }
  int* q1w = (int*)(q1 + (size_t)blockIdx.x * 256 * 128);
  for (int idx = t; idx < 8192; idx += 256)
    q1w[idx] = qti[(idx >> 5) * 34 + (idx & 31)];

  __syncthreads();
  if (t == 0) lastf = (atomicAdd(&st->tick3, 1) == NB1 - 1);
  __syncthreads();
  if (lastf) {
    if (t < C1) {
      int sm = 0; unsigned sq = 0; int mn = 127, mx = -128;
#pragma unroll
      for (int r2 = 0; r2 < NREP; ++r2) {
        sm += atomicAdd(&st->sum1[r2][t], 0);
        sq += atomicAdd(&st->sumsq1[r2][t], 0u);
        mn = min(mn, atomicMin(&st->min1[r2][t], 127));
        mx = max(mx, atomicMax(&st->max1[r2][t], -128));
      }
      float cand = bn_affine_v(sm, sq, mn, mx, gamma1[t], beta1[t], e1,
                               &st->A1[t], &st->B1c[t]);
      for (int off = 32; off; off >>= 1) cand = fmaxf(cand, __shfl_down(cand, off, 64));
      if ((t & 63) == 0) redc[t >> 6] = cand;
    }
    __syncthreads();
    if (t == 0) {
      float rng = fmaxf(redc[0], redc[1]);
      float bwv = ceilf(log2f(rng));
      st->s2 = exp2f(7.0f - bwv);
      st->e2 = bwv - 7.0f;
    }
  }
}

// fused conv2, PROVEN-RESIDENCY SHAPE: 392 blocks of 256 pixels x 256 co at
// (256,2) -- identical deadlock-safety contract to the passing k_conv1f
// (capacity 512 >= 392; LDS ~39KB*2 = 78KB <= 160KB). Rebuild q2 -> qti
// (34.8KB LDS, persists across spin) ONCE. Phase A: MFMA over pixel-group x
// channel-half (acc[4] = 64 regs live) -> absmax2. Spin (tick4). Phase B:
// MFMA again from LDS qti -> quantize -> q3 + replica stats; bn2 ticket
// tail. q3 byte layout linear-identical to round-10 -> k_out unchanged.
__global__ __launch_bounds__(256, 2) void k_conv2f(
    const signed char* __restrict__ q1, const signed char* __restrict__ wq2t,
    signed char* __restrict__ q3, Stats* st, const float* __restrict__ wPW_exp,
    const float* __restrict__ gamma2, const float* __restrict__ beta2,
    float* __restrict__ out) {
  __shared__ int qti[256 * 34];            // 34816 B, persists across spin
  __shared__ int psum[C2], psq[C2], pmn[C2], pmx[C2];
  __shared__ int reda[4];
  __shared__ float red2[4];
  __shared__ int vbro, lastf;
  signed char* qt = (signed char*)qti;

  int t = threadIdx.x, lane = t & 63, wave = t >> 6;
  int half = lane >> 5, l31 = lane & 31;
  size_t g0 = (size_t)blockIdx.x * 256;
  int rep = blockIdx.x & (NREP - 1);

  psum[t] = 0; psq[t] = 0; pmn[t] = 127; pmx[t] = -128;

  int c4 = t & 31;
  float Av[4], Bv[4];
#pragma unroll
  for (int jj = 0; jj < 4; ++jj) {
    Av[jj] = st->A1[c4 * 4 + jj];
    Bv[jj] = st->B1c[c4 * 4 + jj];
  }
  float s2 = st->s2;
  const int* q1w = (const int*)(q1 + g0 * 128);
#pragma unroll
  for (int k = 0; k < 32; ++k) {
    int idx = k * 256 + t;
    int v = q1w[idx];
    int pix = idx >> 5;
    int outv = 0;
#pragma unroll
    for (int jj = 0; jj < 4; ++jj) {
      int b = (signed char)(v >> (8 * jj));
      float y = Av[jj] * (float)b + Bv[jj];
      float r = rintf(y * s2);
      r = fminf(fmaxf(r, -128.f), 127.f);
      r = fmaxf(r, 0.f);
      outv |= ((int)r & 0xff) << (8 * jj);
    }
    qti[pix * 34 + c4] = outv;
  }
  __syncthreads();

  // ---- phase A: absmax2 (acc discarded; 64 acc regs live at a time) ----
  int am2 = 0;
#pragma unroll
  for (int pg = 0; pg < 2; ++pg) {
    int prow = pg * 128 + wave * 32 + l31;
#pragma unroll
    for (int h2 = 0; h2 < 2; ++h2) {
      v16i acc[4];
#pragma unroll
      for (int j = 0; j < 4; ++j)
#pragma unroll
        for (int r = 0; r < 16; ++r) acc[j][r] = 0;
#pragma unroll
      for (int ks = 0; ks < 4; ++ks) {
        v4i af = ld16_lds(&qt[prow * 136 + half * 16 + ks * 32]);
#pragma unroll
        for (int j = 0; j < 4; ++j) {
          v4i bf = *(const v4i*)(wq2t + (size_t)(ks * 2 + half) * 4096 +
                                 ((h2 * 4 + j) * 32 + l31) * 16);
          acc[j] = __builtin_amdgcn_mfma_i32_32x32x32_i8(af, bf, acc[j], 0, 0, 0);
        }
      }
#pragma unroll
      for (int j = 0; j < 4; ++j)
#pragma unroll
        for (int r = 0; r < 16; ++r) am2 = max(am2, abs(acc[j][r]));
    }
  }
  for (int off = 32; off; off >>= 1) am2 = max(am2, __shfl_down(am2, off, 64));
  if (lane == 0) reda[wave] = am2;
  __syncthreads();
  if (t == 0)
    atomicMax(&st->absmax2, max(max(reda[0], reda[1]), max(reda[2], reda[3])));
  __syncthreads();                 // drains vmcnt -> absmax globally performed

  // ---- spin barrier (tick4): 392 blocks, all resident by construction ----
  if (t == 0) {
    atomicAdd(&st->tick4, 1);
    while (atomicAdd(&st->tick4, 0) < NB2C)
      __builtin_amdgcn_s_sleep(8);
    vbro = atomicAdd(&st->absmax2, 0);
  }
  __syncthreads();

  int v2 = vbro;
  int pw = 31 - __clz(v2 | 1);
  int bw = ((v2 & (v2 - 1)) == 0) ? pw : pw + 1;
  int sh2 = max(bw - 7, 0);
  float scale2 = exp2f((float)(-sh2));
  float e3 = st->e2 + wPW_exp[0] + (float)sh2;
  if (blockIdx.x == 0 && t == 0) st->e3 = e3;

  // ---- phase B: MFMA again from LDS qti, quantize, store, stats ----
#pragma unroll
  for (int pg = 0; pg < 2; ++pg) {
    int prow = pg * 128 + wave * 32 + l31;
    int* q3w = (int*)(q3 + (size_t)blockIdx.x * 65536 + pg * 32768);
#pragma unroll
    for (int h2 = 0; h2 < 2; ++h2) {
      v16i acc[4];
#pragma unroll
      for (int j = 0; j < 4; ++j)
#pragma unroll
        for (int r = 0; r < 16; ++r) acc[j][r] = 0;
#pragma unroll
      for (int ks = 0; ks < 4; ++ks) {
        v4i af = ld16_lds(&qt[prow * 136 + half * 16 + ks * 32]);
#pragma unroll
        for (int j = 0; j < 4; ++j) {
          v4i bf = *(const v4i*)(wq2t + (size_t)(ks * 2 + half) * 4096 +
                                 ((h2 * 4 + j) * 32 + l31) * 16);
          acc[j] = __builtin_amdgcn_mfma_i32_32x32x32_i8(af, bf, acc[j], 0, 0, 0);
        }
      }
#pragma unroll
      for (int j = 0; j < 4; ++j) {
        int jg = h2 * 4 + j;
        int c = jg * 32 + l31;
        int sj = 0, sqj = 0, mnj = 127, mxj = -128;
#pragma unroll
        for (int rg = 0; rg < 4; ++rg) {
          int pk = 0;
#pragma unroll
          for (int b = 0; b < 4; ++b) {
            float r = rintf((float)acc[j][4 * rg + b] * scale2);
            r = fminf(fmaxf(r, -128.f), 127.f);
            int qi = (int)r;
            pk |= (qi & 0xff) << (8 * b);
            sj += qi; sqj += qi * qi; mnj = min(mnj, qi); mxj = max(mxj, qi);
          }
          q3w[((wave * 8 + jg) * 4 + rg) * 64 + lane] = pk;
        }
        sj += __shfl_down(sj, 32, 64);
        sqj += __shfl_down(sqj, 32, 64);
        mnj = min(mnj, __shfl_down(mnj, 32, 64));
        mxj = max(mxj, __shfl_down(mxj, 32, 64));
        if (half == 0) {
          atomicAdd(&psum[c], sj); atomicAdd(&psq[c], sqj);
          atomicMin(&pmn[c], mnj); atomicMax(&pmx[c], mxj);
        }
      }
    }
  }
  __syncthreads();
  atomicAdd(&st->sum2[rep][t], psum[t]);
  atomicAdd(&st->sumsq2[rep][t], (unsigned)psq[t]);
  atomicMin(&st->min2[rep][t], pmn[t]);
  atomicMax(&st->max2[rep][t], pmx[t]);

  // ---- last-block bn2 ticket tail (tick2) ----
  __syncthreads();
  if (t == 0) lastf = (atomicAdd(&st->tick2, 1) == NB2C - 1);
  __syncthreads();
  if (lastf) {
    int sm = 0; unsigned sq = 0; int mn = 127, mx = -128;
#pragma unroll
    for (int r2 = 0; r2 < NREP; ++r2) {
      sm += atomicAdd(&st->sum2[r2][t], 0);
      sq += atomicAdd(&st->sumsq2[r2][t], 0u);
      mn = min(mn, atomicMin(&st->min2[r2][t], 127));
      mx = max(mx, atomicMax(&st->max2[r2][t], -128));
    }
    float cand = bn_affine_v(sm, sq, mn, mx, gamma2[t], beta2[t], e3,
                             &st->A2[t], &st->B2c[t]);
    for (int off = 32; off; off >>= 1) cand = fmaxf(cand, __shfl_down(cand, off, 64));
    if (lane == 0) red2[wave] = cand;
    __syncthreads();
    if (t == 0) {
      float rng = fmaxf(fmaxf(red2[0], red2[1]), fmaxf(red2[2], red2[3]));
      float bwv = ceilf(log2f(rng));
      st->sf = exp2f(7.0f - bwv);
      st->ef = bwv - 7.0f;
      out[N2] = bwv - 7.0f;      // final exponent output
    }
  }
}

// final: q3 raw packed (int = 4 consecutive pixels of one channel) -> out
// NCHW float via [c][pix/4] LDS tile (stride 17 dwords, conflict-free).
__global__ __launch_bounds__(256) void k_out(
    const signed char* __restrict__ q3, const Stats* __restrict__ st,
    float* __restrict__ out) {
  __shared__ int ldsc[256 * 17];
  int t = threadIdx.x, lane = t & 63, wave = t >> 6;
  int bid = blockIdx.x;                    // 1568 blocks of 64 pixels
  size_t g0 = (size_t)bid * 64;
  int n = (int)(g0 / HW), p0 = (int)(g0 - (size_t)n * HW);
  const int* q3r = (const int*)(q3 + (size_t)(bid >> 1) * 32768) + (bid & 1) * 4096;
#pragma unroll
  for (int k = 0; k < 16; ++k) {
    int i = k * 256 + t;
    int ln = i & 63, rg = (i >> 6) & 3, j = (i >> 8) & 7, wv = (i >> 11) & 1;
    int v = q3r[i];
    int c = j * 32 + (ln & 31);
    int psub = wv * 8 + 2 * rg + (ln >> 5);
    ldsc[c * 17 + psub] = v;
  }
  __syncthreads();
  float sf = st->sf;
  float* ob = out + (size_t)n * C2 * HW + p0 + lane;
#pragma unroll
  for (int cg = 0; cg < 64; ++cg) {
    int c = wave * 64 + ((cg + wave * 16) & 63);
    int vv = ldsc[c * 17 + (lane >> 2)];
    float y = st->A2[c] * (float)((signed char)(vv >> (8 * (lane & 3)))) + st->B2c[c];
    float r = rintf(y * sf);
    r = fminf(fmaxf(r, -128.f), 127.f);
    ob[(size_t)c * HW] = fmaxf(r, 0.f);
  }
}

extern "C" void kernel_launch(void* const* d_in, const int* in_sizes, int n_in,
                              void* d_out, int out_size, void* d_ws, size_t ws_size,
                              hipStream_t stream) {
  const int* x = (const int*)d_in[0];
  const float* x_exp = (const float*)d_in[1];
  const float* wDW = (const float*)d_in[2];
  const float* wDW_exp = (const float*)d_in[3];
  const float* wPW = (const float*)d_in[4];
  const float* wPW_exp = (const float*)d_in[5];
  const float* gamma1 = (const float*)d_in[6];
  const float* beta1 = (const float*)d_in[7];
  const float* gamma2 = (const float*)d_in[8];
  const float* beta2 = (const float*)d_in[9];
  float* out = (float*)d_out;

  char* ws = (char*)d_ws;
  signed char* xp2 = (signed char*)(ws + OFF_XP);
  signed char* q1 = (signed char*)(ws + OFF_Q1);
  signed char* q3 = (signed char*)(ws + OFF_Q3);
  signed char* wq1t = (signed char*)(ws + OFF_WQ1);
  signed char* wq2t = (signed char*)(ws + OFF_WQ2);
  Stats* st = (Stats*)(ws + OFF_STATS);

  hipLaunchKernelGGL(k_pre, dim3(2561), dim3(256), 0, stream,
                     x, xp2, wDW, wq1t, wPW, wq2t, st);
  hipLaunchKernelGGL(k_conv1f, dim3(NB1), dim3(256), 0, stream,
                     xp2, wq1t, q1, st, x_exp, wDW_exp, gamma1, beta1);
  hipLaunchKernelGGL(k_conv2f, dim3(NB2C), dim3(256), 0, stream,
                     q1, wq2t, q3, st, wPW_exp, gamma2, beta2, out);
  hipLaunchKernelGGL(k_out, dim3(1568), dim3(256), 0, stream, q3, st, out);
}

// Round 13
// 261.425 us; speedup vs baseline: 1.0170x; 1.0170x over previous
//
#include <hip/hip_runtime.h>
#include <cstdint>
#include <cstddef>

#define C1 128
#define C2 256
#define Hh 56
#define Wd 56
#define HW 3136                  // 56*56
#define NHW 100352               // 32*3136
#define N1 ((size_t)12845056)    // 32*128*3136
#define N2 ((size_t)25690112)    // 32*256*3136
#define XPSZ ((size_t)13778944)  // 32*58*58*128
#define NREP 8                   // stat-accumulator replicas (cache-line spread)
#define NB1 392                  // conv1 grid (256-pixel tiles)
#define NB2C 392                 // conv2 grid (256-pixel tiles) -- proven-residency shape

typedef int v4i __attribute__((ext_vector_type(4)));
typedef int v16i __attribute__((ext_vector_type(16)));

// ---- workspace layout (bytes) ----
static constexpr size_t OFF_XP = 0;
static constexpr size_t OFF_Q1 = XPSZ;
static constexpr size_t OFF_Q3 = OFF_Q1 + N1;
static constexpr size_t OFF_WQ1 = OFF_Q3 + N2;
static constexpr size_t OFF_WQ2 = OFF_WQ1 + 147456;
static constexpr size_t OFF_STATS = OFF_WQ2 + 32768;

// tick counters each on their own 128B line (spin-polled); absmax separate.
struct Stats {
  int absmax1, absmax2, pad0, pad1;
  float scale1, e1, s2, e2;
  float scaleq2, e3, sf, ef;
  int padA[20];
  int tick1, padB[31];     // conv1 spin barrier
  int tick2, padC[31];     // conv2 bn2 ticket tail
  int tick3, padD[31];     // conv1 bn1 ticket tail
  int tick4, padE[31];     // conv2 spin barrier
  int sum1[NREP][C1]; unsigned sumsq1[NREP][C1];
  int min1[NREP][C1], max1[NREP][C1];
  float A1[C1], B1c[C1];
  int sum2[NREP][C2]; unsigned sumsq2[NREP][C2];
  int min2[NREP][C2], max2[NREP][C2];
  float A2[C2], B2c[C2];
};

// ---- one merged prep dispatch ----
// transpose section vectorized: x read as int4 (16B/lane, 224B contiguous
// runs per channel; 7 iters/thread vs 28 scalar). G13: scalar loads were
// the last unvectorized memory path in the pipeline. LDS byte-writes land
// 2-way bank-aliased (free, m136). Output bytes identical to scalar version.
__global__ __launch_bounds__(256) void k_pre(
    const int* __restrict__ x, signed char* __restrict__ xp,
    const float* __restrict__ wDW, signed char* __restrict__ wq1t,
    const float* __restrict__ wPW, signed char* __restrict__ wq2t,
    Stats* st) {
  __shared__ signed char lds[56 * 132];
  int t = threadIdx.x, bid = blockIdx.x;
  if (bid < 1856) {
    int hh = bid % 58, n = bid / 58;
    int* xpw = (int*)(xp + ((size_t)n * 58 + hh) * 7424);
    if (hh == 0 || hh == 57) {
      for (int o = t; o < 1856; o += 256) xpw[o] = 0;
      return;
    }
    int h = hh - 1;
    const int4* xb4 = (const int4*)(x + (size_t)n * C1 * HW + h * 56);
    // 128 c x 14 int4 = 1792 vector loads (HW=3136 and h*56 both /4)
    for (int idx = t; idx < 1792; idx += 256) {
      int c = idx / 14, wq = idx - c * 14;
      int4 v = xb4[(size_t)c * 784 + wq];
      int w = wq * 4;
      lds[(w + 0) * 132 + c] = (signed char)v.x;
      lds[(w + 1) * 132 + c] = (signed char)v.y;
      lds[(w + 2) * 132 + c] = (signed char)v.z;
      lds[(w + 3) * 132 + c] = (signed char)v.w;
    }
    __syncthreads();
    for (int o = t; o < 1856; o += 256) {
      int kb = o / 232, r = o - kb * 232, ww = r >> 2, cw = r & 3;
      int val = (ww == 0 || ww == 57) ? 0
                : *(const int*)&lds[(ww - 1) * 132 + kb * 16 + cw * 4];
      xpw[o] = val;
    }
    return;
  }
  if (bid < 2432) {
    int idx = (bid - 1856) * 256 + t;
    int co = idx / 1152, r = idx - co * 1152;
    int ci = r / 9, pos = r - ci * 9;
    int k = pos * 128 + ci;
    wq1t[(size_t)(k >> 4) * 2048 + co * 16 + (k & 15)] = (signed char)(int)wDW[idx];
    return;
  }
  if (bid < 2560) {
    int i = (bid - 2432) * 256 + t;
    int co = i >> 7, ci = i & 127;
    wq2t[(size_t)(ci >> 4) * 4096 + co * 16 + (ci & 15)] = (signed char)(int)wPW[i];
    return;
  }
  if (t == 0) {
    st->absmax1 = 0; st->absmax2 = 0;
    st->tick1 = 0; st->tick2 = 0; st->tick3 = 0; st->tick4 = 0;
  }
  for (int c = t; c < NREP * C1; c += 256) {
    ((int*)st->sum1)[c] = 0; ((unsigned*)st->sumsq1)[c] = 0u;
    ((int*)st->min1)[c] = 127; ((int*)st->max1)[c] = -128;
  }
  for (int c = t; c < NREP * C2; c += 256) {
    ((int*)st->sum2)[c] = 0; ((unsigned*)st->sumsq2)[c] = 0u;
    ((int*)st->min2)[c] = 127; ((int*)st->max2)[c] = -128;
  }
}

__device__ inline v4i ld16_lds(const signed char* p) {
  const int2* q = (const int2*)p;          // 8-byte aligned
  int2 lo = q[0], hi = q[1];
  v4i r; r[0] = lo.x; r[1] = lo.y; r[2] = hi.x; r[3] = hi.y;
  return r;
}

// bn affine from scalar stats (single call site per layer -> deterministic).
__device__ inline float bn_affine_v(int sum, unsigned sumsq, int mn, int mx,
                                    float g, float b, float e_in,
                                    float* Aout, float* Bout) {
  double meanq = (double)sum / (double)NHW;
  double varq = (double)sumsq / (double)NHW - meanq * meanq;
  float se = exp2f(e_in);
  float mean = (float)meanq * se;
  float var = (float)varq * se * se;
  float rsq = 1.0f / sqrtf(var + 1e-5f);
  float Avv = g * se * rsq;
  float Bvv = b - g * mean * rsq;
  *Aout = Avv; *Bout = Bvv;
  return fmaxf(fabsf(Avv * (float)mn + Bvv), fabsf(Avv * (float)mx + Bvv));
}

// shared conv1 MFMA body: 3x3 conv 128->128, block = 256 pixels x 128 co.
__device__ inline void conv1_mfma(const signed char* __restrict__ xp,
                                  const signed char* __restrict__ wq1t,
                                  int bx, int t, v16i a1[2][4]) {
  int lane = t & 63, wave = t >> 6;
  int half = lane >> 5, l31 = lane & 31;
  size_t g0 = (size_t)bx * 256;

  const signed char* ab[2];
#pragma unroll
  for (int i = 0; i < 2; ++i) {
    size_t gm = g0 + wave * 64 + i * 32 + l31;
    int n = (int)(gm / HW);
    int p = (int)(gm - (size_t)n * HW);
    int h = p / 56, w = p - h * 56;
    ab[i] = xp + ((size_t)n * 58 + h) * 7424 + w * 16 + half * 928;
  }
  const signed char* bb[4];
#pragma unroll
  for (int j = 0; j < 4; ++j)
    bb[j] = wq1t + (size_t)(j * 32 + l31) * 16 + half * 2048;

#pragma unroll
  for (int i = 0; i < 2; ++i)
#pragma unroll
    for (int j = 0; j < 4; ++j)
#pragma unroll
      for (int r = 0; r < 16; ++r) a1[i][j][r] = 0;

#pragma unroll
  for (int pos = 0; pos < 9; ++pos) {
    int kh = pos / 3, kw = pos - kh * 3;
    const signed char* a0p = ab[0] + kh * 7424 + kw * 16;
    const signed char* a1p = ab[1] + kh * 7424 + kw * 16;
#pragma unroll
    for (int kb = 0; kb < 8; kb += 2) {
      v4i af0 = *(const v4i*)(a0p + kb * 928);
      v4i af1 = *(const v4i*)(a1p + kb * 928);
      v4i bf[4];
#pragma unroll
      for (int j = 0; j < 4; ++j)
        bf[j] = *(const v4i*)(bb[j] + pos * 16384 + kb * 2048);
#pragma unroll
      for (int j = 0; j < 4; ++j) {
        a1[0][j] = __builtin_amdgcn_mfma_i32_32x32x32_i8(af0, bf[j], a1[0][j], 0, 0, 0);
        a1[1][j] = __builtin_amdgcn_mfma_i32_32x32x32_i8(af1, bf[j], a1[1][j], 0, 0, 0);
      }
    }
  }
}

// fused conv1: MFMA -> absmax1 -> in-kernel spin barrier -> quantize from
// registers -> q1 + replica stats -> bn1 ticket tail. (round-10 verified)
// DEADLOCK SAFETY: 392 blocks at (256,2) -> capacity 512 >= 392.
__global__ __launch_bounds__(256, 2) void k_conv1f(
    const signed char* __restrict__ xp, const signed char* __restrict__ wq1t,
    signed char* __restrict__ q1, Stats* st,
    const float* __restrict__ x_exp, const float* __restrict__ wDW_exp,
    const float* __restrict__ gamma1, const float* __restrict__ beta1) {
  __shared__ int reda[4];
  __shared__ int vbro;
  __shared__ int qti[256 * 34];            // 256 pixels x 136B
  __shared__ int psum[C1], psq[C1], pmn[C1], pmx[C1];
  __shared__ float redc[2];
  __shared__ int lastf;
  signed char* qt = (signed char*)qti;
  int t = threadIdx.x, lane = t & 63, wave = t >> 6;
  int half = lane >> 5, l31 = lane & 31;
  int rep = blockIdx.x & (NREP - 1);

  v16i a1[2][4];
  conv1_mfma(xp, wq1t, blockIdx.x, t, a1);

  int am = 0;
#pragma unroll
  for (int i = 0; i < 2; ++i)
#pragma unroll
    for (int j = 0; j < 4; ++j)
#pragma unroll
      for (int r = 0; r < 16; ++r) am = max(am, abs(a1[i][j][r]));
  for (int off = 32; off; off >>= 1) am = max(am, __shfl_down(am, off, 64));
  if (lane == 0) reda[wave] = am;
  if (t < C1) { psum[t] = 0; psq[t] = 0; pmn[t] = 127; pmx[t] = -128; }
  __syncthreads();
  if (t == 0)
    atomicMax(&st->absmax1, max(max(reda[0], reda[1]), max(reda[2], reda[3])));
  __syncthreads();                 // drains vmcnt -> absmax globally performed

  if (t == 0) {
    atomicAdd(&st->tick1, 1);
    while (atomicAdd(&st->tick1, 0) < NB1)
      __builtin_amdgcn_s_sleep(8);
    vbro = atomicAdd(&st->absmax1, 0);
  }
  __syncthreads();

  int v1 = vbro;
  int pw = 31 - __clz(v1 | 1);
  int bw = ((v1 & (v1 - 1)) == 0) ? pw : pw + 1;
  int sh = max(bw - 7, 0);
  float scale1 = exp2f((float)(-sh));
  float e1 = x_exp[0] + wDW_exp[0] + (float)sh;
  if (blockIdx.x == 0 && t == 0) st->e1 = e1;

#pragma unroll
  for (int j = 0; j < 4; ++j) {
    int sj = 0, sqj = 0, mnj = 127, mxj = -128;
    int c = j * 32 + l31;
#pragma unroll
    for (int i = 0; i < 2; ++i)
#pragma unroll
      for (int reg = 0; reg < 16; ++reg) {
        int av = a1[i][j][reg];
        int row = (reg & 3) + 8 * (reg >> 2) + 4 * half;
        int pix = wave * 64 + i * 32 + row;
        float r = rintf((float)av * scale1);
        r = fminf(fmaxf(r, -128.f), 127.f);
        int qi = (int)r;
        qt[pix * 136 + c] = (signed char)qi;
        sj += qi; sqj += qi * qi; mnj = min(mnj, qi); mxj = max(mxj, qi);
      }
    sj += __shfl_down(sj, 32, 64);
    sqj += __shfl_down(sqj, 32, 64);
    mnj = min(mnj, __shfl_down(mnj, 32, 64));
    mxj = max(mxj, __shfl_down(mxj, 32, 64));
    if (half == 0) {
      atomicAdd(&psum[c], sj); atomicAdd(&psq[c], sqj);
      atomicMin(&pmn[c], mnj); atomicMax(&pmx[c], mxj);
    }
  }
  __syncthreads();
  if (t < C1) {
    atomicAdd(&st->sum1[rep][t], psum[t]);
    atomicAdd(&st->sumsq1[rep][t], (unsigned)psq[t]);
    atomicMin(&st->min1[rep][t], pmn[t]);
    atomicMax(&st->max1[rep][t], pmx[t]);
  }
  int* q1w = (int*)(q1 + (size_t)blockIdx.x * 256 * 128);
  for (int idx = t; idx < 8192; idx += 256)
    q1w[idx] = qti[(idx >> 5) * 34 + (idx & 31)];

  __syncthreads();
  if (t == 0) lastf = (atomicAdd(&st->tick3, 1) == NB1 - 1);
  __syncthreads();
  if (lastf) {
    if (t < C1) {
      int sm = 0; unsigned sq = 0; int mn = 127, mx = -128;
#pragma unroll
      for (int r2 = 0; r2 < NREP; ++r2) {
        sm += atomicAdd(&st->sum1[r2][t], 0);
        sq += atomicAdd(&st->sumsq1[r2][t], 0u);
        mn = min(mn, atomicMin(&st->min1[r2][t], 127));
        mx = max(mx, atomicMax(&st->max1[r2][t], -128));
      }
      float cand = bn_affine_v(sm, sq, mn, mx, gamma1[t], beta1[t], e1,
                               &st->A1[t], &st->B1c[t]);
      for (int off = 32; off; off >>= 1) cand = fmaxf(cand, __shfl_down(cand, off, 64));
      if ((t & 63) == 0) redc[t >> 6] = cand;
    }
    __syncthreads();
    if (t == 0) {
      float rng = fmaxf(redc[0], redc[1]);
      float bwv = ceilf(log2f(rng));
      st->s2 = exp2f(7.0f - bwv);
      st->e2 = bwv - 7.0f;
    }
  }
}

// fused conv2, proven-residency shape: 392 blocks of 256 pixels x 256 co at
// (256,2) (capacity 512 >= 392; LDS ~39KB*2 = 78KB <= 160KB). Rebuild q2 ->
// qti (34.8KB LDS, persists across spin) ONCE. Phase A: MFMA (acc[4] live)
// -> absmax2. Spin (tick4). Phase B: MFMA again from LDS qti -> quantize ->
// q3 + replica stats; bn2 ticket tail. (round-12 verified)
__global__ __launch_bounds__(256, 2) void k_conv2f(
    const signed char* __restrict__ q1, const signed char* __restrict__ wq2t,
    signed char* __restrict__ q3, Stats* st, const float* __restrict__ wPW_exp,
    const float* __restrict__ gamma2, const float* __restrict__ beta2,
    float* __restrict__ out) {
  __shared__ int qti[256 * 34];            // 34816 B, persists across spin
  __shared__ int psum[C2], psq[C2], pmn[C2], pmx[C2];
  __shared__ int reda[4];
  __shared__ float red2[4];
  __shared__ int vbro, lastf;
  signed char* qt = (signed char*)qti;

  int t = threadIdx.x, lane = t & 63, wave = t >> 6;
  int half = lane >> 5, l31 = lane & 31;
  size_t g0 = (size_t)blockIdx.x * 256;
  int rep = blockIdx.x & (NREP - 1);

  psum[t] = 0; psq[t] = 0; pmn[t] = 127; pmx[t] = -128;

  int c4 = t & 31;
  float Av[4], Bv[4];
#pragma unroll
  for (int jj = 0; jj < 4; ++jj) {
    Av[jj] = st->A1[c4 * 4 + jj];
    Bv[jj] = st->B1c[c4 * 4 + jj];
  }
  float s2 = st->s2;
  const int* q1w = (const int*)(q1 + g0 * 128);
#pragma unroll
  for (int k = 0; k < 32; ++k) {
    int idx = k * 256 + t;
    int v = q1w[idx];
    int pix = idx >> 5;
    int outv = 0;
#pragma unroll
    for (int jj = 0; jj < 4; ++jj) {
      int b = (signed char)(v >> (8 * jj));
      float y = Av[jj] * (float)b + Bv[jj];
      float r = rintf(y * s2);
      r = fminf(fmaxf(r, -128.f), 127.f);
      r = fmaxf(r, 0.f);
      outv |= ((int)r & 0xff) << (8 * jj);
    }
    qti[pix * 34 + c4] = outv;
  }
  __syncthreads();

  // ---- phase A: absmax2 (acc discarded; 64 acc regs live at a time) ----
  int am2 = 0;
#pragma unroll
  for (int pg = 0; pg < 2; ++pg) {
    int prow = pg * 128 + wave * 32 + l31;
#pragma unroll
    for (int h2 = 0; h2 < 2; ++h2) {
      v16i acc[4];
#pragma unroll
      for (int j = 0; j < 4; ++j)
#pragma unroll
        for (int r = 0; r < 16; ++r) acc[j][r] = 0;
#pragma unroll
      for (int ks = 0; ks < 4; ++ks) {
        v4i af = ld16_lds(&qt[prow * 136 + half * 16 + ks * 32]);
#pragma unroll
        for (int j = 0; j < 4; ++j) {
          v4i bf = *(const v4i*)(wq2t + (size_t)(ks * 2 + half) * 4096 +
                                 ((h2 * 4 + j) * 32 + l31) * 16);
          acc[j] = __builtin_amdgcn_mfma_i32_32x32x32_i8(af, bf, acc[j], 0, 0, 0);
        }
      }
#pragma unroll
      for (int j = 0; j < 4; ++j)
#pragma unroll
        for (int r = 0; r < 16; ++r) am2 = max(am2, abs(acc[j][r]));
    }
  }
  for (int off = 32; off; off >>= 1) am2 = max(am2, __shfl_down(am2, off, 64));
  if (lane == 0) reda[wave] = am2;
  __syncthreads();
  if (t == 0)
    atomicMax(&st->absmax2, max(max(reda[0], reda[1]), max(reda[2], reda[3])));
  __syncthreads();                 // drains vmcnt -> absmax globally performed

  // ---- spin barrier (tick4): 392 blocks, all resident by construction ----
  if (t == 0) {
    atomicAdd(&st->tick4, 1);
    while (atomicAdd(&st->tick4, 0) < NB2C)
      __builtin_amdgcn_s_sleep(8);
    vbro = atomicAdd(&st->absmax2, 0);
  }
  __syncthreads();

  int v2 = vbro;
  int pw = 31 - __clz(v2 | 1);
  int bw = ((v2 & (v2 - 1)) == 0) ? pw : pw + 1;
  int sh2 = max(bw - 7, 0);
  float scale2 = exp2f((float)(-sh2));
  float e3 = st->e2 + wPW_exp[0] + (float)sh2;
  if (blockIdx.x == 0 && t == 0) st->e3 = e3;

  // ---- phase B: MFMA again from LDS qti, quantize, store, stats ----
#pragma unroll
  for (int pg = 0; pg < 2; ++pg) {
    int prow = pg * 128 + wave * 32 + l31;
    int* q3w = (int*)(q3 + (size_t)blockIdx.x * 65536 + pg * 32768);
#pragma unroll
    for (int h2 = 0; h2 < 2; ++h2) {
      v16i acc[4];
#pragma unroll
      for (int j = 0; j < 4; ++j)
#pragma unroll
        for (int r = 0; r < 16; ++r) acc[j][r] = 0;
#pragma unroll
      for (int ks = 0; ks < 4; ++ks) {
        v4i af = ld16_lds(&qt[prow * 136 + half * 16 + ks * 32]);
#pragma unroll
        for (int j = 0; j < 4; ++j) {
          v4i bf = *(const v4i*)(wq2t + (size_t)(ks * 2 + half) * 4096 +
                                 ((h2 * 4 + j) * 32 + l31) * 16);
          acc[j] = __builtin_amdgcn_mfma_i32_32x32x32_i8(af, bf, acc[j], 0, 0, 0);
        }
      }
#pragma unroll
      for (int j = 0; j < 4; ++j) {
        int jg = h2 * 4 + j;
        int c = jg * 32 + l31;
        int sj = 0, sqj = 0, mnj = 127, mxj = -128;
#pragma unroll
        for (int rg = 0; rg < 4; ++rg) {
          int pk = 0;
#pragma unroll
          for (int b = 0; b < 4; ++b) {
            float r = rintf((float)acc[j][4 * rg + b] * scale2);
            r = fminf(fmaxf(r, -128.f), 127.f);
            int qi = (int)r;
            pk |= (qi & 0xff) << (8 * b);
            sj += qi; sqj += qi * qi; mnj = min(mnj, qi); mxj = max(mxj, qi);
          }
          q3w[((wave * 8 + jg) * 4 + rg) * 64 + lane] = pk;
        }
        sj += __shfl_down(sj, 32, 64);
        sqj += __shfl_down(sqj, 32, 64);
        mnj = min(mnj, __shfl_down(mnj, 32, 64));
        mxj = max(mxj, __shfl_down(mxj, 32, 64));
        if (half == 0) {
          atomicAdd(&psum[c], sj); atomicAdd(&psq[c], sqj);
          atomicMin(&pmn[c], mnj); atomicMax(&pmx[c], mxj);
        }
      }
    }
  }
  __syncthreads();
  atomicAdd(&st->sum2[rep][t], psum[t]);
  atomicAdd(&st->sumsq2[rep][t], (unsigned)psq[t]);
  atomicMin(&st->min2[rep][t], pmn[t]);
  atomicMax(&st->max2[rep][t], pmx[t]);

  // ---- last-block bn2 ticket tail (tick2) ----
  __syncthreads();
  if (t == 0) lastf = (atomicAdd(&st->tick2, 1) == NB2C - 1);
  __syncthreads();
  if (lastf) {
    int sm = 0; unsigned sq = 0; int mn = 127, mx = -128;
#pragma unroll
    for (int r2 = 0; r2 < NREP; ++r2) {
      sm += atomicAdd(&st->sum2[r2][t], 0);
      sq += atomicAdd(&st->sumsq2[r2][t], 0u);
      mn = min(mn, atomicMin(&st->min2[r2][t], 127));
      mx = max(mx, atomicMax(&st->max2[r2][t], -128));
    }
    float cand = bn_affine_v(sm, sq, mn, mx, gamma2[t], beta2[t], e3,
                             &st->A2[t], &st->B2c[t]);
    for (int off = 32; off; off >>= 1) cand = fmaxf(cand, __shfl_down(cand, off, 64));
    if (lane == 0) red2[wave] = cand;
    __syncthreads();
    if (t == 0) {
      float rng = fmaxf(fmaxf(red2[0], red2[1]), fmaxf(red2[2], red2[3]));
      float bwv = ceilf(log2f(rng));
      st->sf = exp2f(7.0f - bwv);
      st->ef = bwv - 7.0f;
      out[N2] = bwv - 7.0f;      // final exponent output
    }
  }
}

// final: q3 raw packed (int = 4 consecutive pixels of one channel) -> out
// NCHW float via [c][pix/4] LDS tile (stride 17 dwords, conflict-free).
__global__ __launch_bounds__(256) void k_out(
    const signed char* __restrict__ q3, const Stats* __restrict__ st,
    float* __restrict__ out) {
  __shared__ int ldsc[256 * 17];
  int t = threadIdx.x, lane = t & 63, wave = t >> 6;
  int bid = blockIdx.x;                    // 1568 blocks of 64 pixels
  size_t g0 = (size_t)bid * 64;
  int n = (int)(g0 / HW), p0 = (int)(g0 - (size_t)n * HW);
  const int* q3r = (const int*)(q3 + (size_t)(bid >> 1) * 32768) + (bid & 1) * 4096;
#pragma unroll
  for (int k = 0; k < 16; ++k) {
    int i = k * 256 + t;
    int ln = i & 63, rg = (i >> 6) & 3, j = (i >> 8) & 7, wv = (i >> 11) & 1;
    int v = q3r[i];
    int c = j * 32 + (ln & 31);
    int psub = wv * 8 + 2 * rg + (ln >> 5);
    ldsc[c * 17 + psub] = v;
  }
  __syncthreads();
  float sf = st->sf;
  float* ob = out + (size_t)n * C2 * HW + p0 + lane;
#pragma unroll
  for (int cg = 0; cg < 64; ++cg) {
    int c = wave * 64 + ((cg + wave * 16) & 63);
    int vv = ldsc[c * 17 + (lane >> 2)];
    float y = st->A2[c] * (float)((signed char)(vv >> (8 * (lane & 3)))) + st->B2c[c];
    float r = rintf(y * sf);
    r = fminf(fmaxf(r, -128.f), 127.f);
    ob[(size_t)c * HW] = fmaxf(r, 0.f);
  }
}

extern "C" void kernel_launch(void* const* d_in, const int* in_sizes, int n_in,
                              void* d_out, int out_size, void* d_ws, size_t ws_size,
                              hipStream_t stream) {
  const int* x = (const int*)d_in[0];
  const float* x_exp = (const float*)d_in[1];
  const float* wDW = (const float*)d_in[2];
  const float* wDW_exp = (const float*)d_in[3];
  const float* wPW = (const float*)d_in[4];
  const float* wPW_exp = (const float*)d_in[5];
  const float* gamma1 = (const float*)d_in[6];
  const float* beta1 = (const float*)d_in[7];
  const float* gamma2 = (const float*)d_in[8];
  const float* beta2 = (const float*)d_in[9];
  float* out = (float*)d_out;

  char* ws = (char*)d_ws;
  signed char* xp2 = (signed char*)(ws + OFF_XP);
  signed char* q1 = (signed char*)(ws + OFF_Q1);
  signed char* q3 = (signed char*)(ws + OFF_Q3);
  signed char* wq1t = (signed char*)(ws + OFF_WQ1);
  signed char* wq2t = (signed char*)(ws + OFF_WQ2);
  Stats* st = (Stats*)(ws + OFF_STATS);

  hipLaunchKernelGGL(k_pre, dim3(2561), dim3(256), 0, stream,
                     x, xp2, wDW, wq1t, wPW, wq2t, st);
  hipLaunchKernelGGL(k_conv1f, dim3(NB1), dim3(256), 0, stream,
                     xp2, wq1t, q1, st, x_exp, wDW_exp, gamma1, beta1);
  hipLaunchKernelGGL(k_conv2f, dim3(NB2C), dim3(256), 0, stream,
                     q1, wq2t, q3, st, wPW_exp, gamma2, beta2, out);
  hipLaunchKernelGGL(k_out, dim3(1568), dim3(256), 0, stream, q3, st, out);
}